// Round 12
// baseline (201.902 us; speedup 1.0000x reference)
//
#include <hip/hip_runtime.h>

#define CC 512
#define NPIX 4096
#define NB 2
#define NG 32
#define GSIZE 16
#define EPS 1e-6f

typedef unsigned short u16;
typedef __bf16 bf16x8 __attribute__((ext_vector_type(8)));
typedef float f32x4 __attribute__((ext_vector_type(4)));

__device__ __forceinline__ float bf2f(u16 u) {
  union { unsigned int i; float f; } c; c.i = ((unsigned int)u) << 16; return c.f;
}
__device__ __forceinline__ u16 f2bf(float f) {
  union { float f; unsigned int i; } c; c.f = f;
  unsigned int u = c.i;
  return (u16)((u + 0x7fffu + ((u >> 16) & 1u)) >> 16);
}

// ---- plain fp32 -> bf16 convert (one 512x512 matrix) ----
__global__ __launch_bounds__(256) void f2bf1_kernel(const float* __restrict__ s,
                                                    u16* __restrict__ d) {
  int i = blockIdx.x * 256 + threadIdx.x;
  float4 v = ((const float4*)s)[i];
  uint2 pk;
  pk.x = (unsigned)f2bf(v.x) | ((unsigned)f2bf(v.y) << 16);
  pk.y = (unsigned)f2bf(v.z) | ((unsigned)f2bf(v.w) << 16);
  ((uint2*)d)[i] = pk;
}

// ---- transposed fp32 -> bf16 convert: d[a][b] = f2bf(s[b][a]), 512x512 ----
__global__ __launch_bounds__(256) void f2bfT_kernel(
    const float* __restrict__ s0, const float* __restrict__ s1,
    const float* __restrict__ s2,
    u16* __restrict__ d0, u16* __restrict__ d1, u16* __restrict__ d2) {
  const float* s; u16* d;
  switch (blockIdx.z) {
    case 0: s = s0; d = d0; break;
    case 1: s = s1; d = d1; break;
    default: s = s2; d = d2; break;
  }
  __shared__ float tile[64][65];
  int a0 = blockIdx.x * 64, b0 = blockIdx.y * 64;
  int tx = threadIdx.x & 63, w = threadIdx.x >> 6;
  #pragma unroll
  for (int r = 0; r < 16; ++r) {
    int row = w * 16 + r;
    tile[row][tx] = s[(long)(b0 + row) * CC + a0 + tx];
  }
  __syncthreads();
  #pragma unroll
  for (int r = 0; r < 16; ++r) {
    int row = w * 16 + r;
    d[(long)(a0 + row) * CC + b0 + tx] = f2bf(tile[tx][row]);
  }
}

// ---- u[b] = sum_c wkT[b,c] * bq[c]  (column-bias helper) ----
__global__ __launch_bounds__(256) void ubias_kernel(const u16* __restrict__ wkT,
                                                    const float* __restrict__ bq,
                                                    float* __restrict__ u) {
  int b = blockIdx.x * 256 + threadIdx.x;
  const u16* row = wkT + (long)b * CC;
  float s = 0.f;
  for (int c = 0; c < CC; c += 8) {
    uint4 raw = *(const uint4*)(row + c);
    const u16* pr = (const u16*)&raw;
    #pragma unroll
    for (int k = 0; k < 8; ++k) s += bf2f(pr[k]) * bq[c + k];
  }
  u[b] = s;
}

// ---- wobv[o] = bo[o] + sum_c wo[o,c] * bv[c] ----
__global__ __launch_bounds__(256) void wobv_kernel(const float* __restrict__ wo,
                                                   const float* __restrict__ bv,
                                                   const float* __restrict__ bo,
                                                   float* __restrict__ wobv) {
  int o = blockIdx.x * 256 + threadIdx.x;
  const float* row = wo + (long)o * CC;
  float s = bo[o];
  for (int c = 0; c < CC; c += 4) {
    float4 v = *(const float4*)(row + c);
    s += v.x * bv[c] + v.y * bv[c + 1] + v.z * bv[c + 2] + v.w * bv[c + 3];
  }
  wobv[o] = s;
}

// ---- cb[bz*NPIX+j] = scale * sum_b hn[bz,j,b] * u[b] ----
__global__ __launch_bounds__(256) void cb_kernel(const u16* __restrict__ hn,
                                                 const float* __restrict__ u,
                                                 float* __restrict__ cb, float scale) {
  int i = blockIdx.x * 256 + threadIdx.x;
  const u16* row = hn + (long)i * CC;
  float s = 0.f;
  for (int c = 0; c < CC; c += 8) {
    uint4 raw = *(const uint4*)(row + c);
    const u16* pr = (const u16*)&raw;
    #pragma unroll
    for (int k = 0; k < 8; ++k) s += bf2f(pr[k]) * u[c + k];
  }
  cb[i] = s * scale;
}

// ---- GroupNorm stats: one block per (b,g), 16*4096 contiguous floats ----
__global__ __launch_bounds__(256) void gn_stats_kernel(const float* __restrict__ x,
                                                       float* __restrict__ stats) {
  int bg = blockIdx.x;
  const float4* p = (const float4*)(x + (long)bg * (GSIZE * NPIX));
  float s = 0.f, ss = 0.f;
  for (int i = threadIdx.x; i < GSIZE * NPIX / 4; i += 256) {
    float4 v = p[i];
    s  += v.x + v.y + v.z + v.w;
    ss += v.x * v.x + v.y * v.y + v.z * v.z + v.w * v.w;
  }
  for (int off = 32; off; off >>= 1) { s += __shfl_xor(s, off); ss += __shfl_xor(ss, off); }
  __shared__ float rs[4], rss[4];
  int wid = threadIdx.x >> 6;
  if ((threadIdx.x & 63) == 0) { rs[wid] = s; rss[wid] = ss; }
  __syncthreads();
  if (threadIdx.x == 0) {
    s = rs[0] + rs[1] + rs[2] + rs[3];
    ss = rss[0] + rss[1] + rss[2] + rss[3];
    float mean = s / (float)(GSIZE * NPIX);
    float var = ss / (float)(GSIZE * NPIX) - mean * mean;
    stats[bg * 2] = mean;
    stats[bg * 2 + 1] = rsqrtf(var + EPS);
  }
}

// ---- GN apply + transpose: x[b][c][n] -> hn[b][n][c] (bf16) ----
__global__ __launch_bounds__(256) void gn_apply_kernel(const float* __restrict__ x,
                                                       const float* __restrict__ stats,
                                                       const float* __restrict__ gw,
                                                       const float* __restrict__ gb,
                                                       u16* __restrict__ hn) {
  int n0 = blockIdx.x * 64, c0 = blockIdx.y * 64, b = blockIdx.z;
  __shared__ float tile[64][65];
  int t = threadIdx.x;
  int nj = t & 63, cw = t >> 6;
  #pragma unroll
  for (int r = 0; r < 16; ++r) {
    int ci = cw * 16 + r;
    int c = c0 + ci;
    float mean = stats[(b * NG + (c >> 4)) * 2];
    float rstd = stats[(b * NG + (c >> 4)) * 2 + 1];
    float v = x[((long)b * CC + c) * NPIX + n0 + nj];
    tile[ci][nj] = (v - mean) * rstd * gw[c] + gb[c];
  }
  __syncthreads();
  #pragma unroll
  for (int r = 0; r < 16; ++r) {
    int nn = cw * 16 + r;
    hn[((long)b * NPIX + n0 + nn) * CC + c0 + nj] = f2bf(tile[nj][nn]);
  }
}

// ---- reduce 16 per-bx partial rowsums into L[bz][row] ----
__global__ __launch_bounds__(256) void lred_kernel(const float* __restrict__ Lp,
                                                   float* __restrict__ L) {
  int i = blockIdx.x * 256 + threadIdx.x;  // bz*NPIX + row
  int bz = i / NPIX, row = i % NPIX;
  float s = 0.f;
  #pragma unroll
  for (int b = 0; b < 16; ++b) s += Lp[((long)bz * 16 + b) * NPIX + row];
  L[i] = s;
}

// ---- 128x128 NT GEMM (2-phase counted-vmcnt) ----
// EPI: 0 = plain bf16/f32 (+bias/resid per BIASMODE/RESID)
//      1 = exp(acc*scale + cb[col]) bf16 + rowsum atomics into L
//      3 = fused attention output: f32 = acc/L[col] + bias[row] + resid
#define BM 128
#define BN 128
#define BKT 64
#define BUFSZ 8192  // u16 per half-buffer (one 128x64 operand tile)

template<int OUTF32, int BIASMODE, int RESID, int EPI>
__global__ __launch_bounds__(256) void gemm_nt(
    const u16* __restrict__ A, int lda, long aBatch,
    const u16* __restrict__ B, int ldb, long bBatch,
    void* __restrict__ C, int ldc, long cBatch,
    const float* __restrict__ bias,
    const float* __restrict__ resid, long rBatch,
    float* __restrict__ L, int lOff,
    const float* __restrict__ cbias,
    int K, float scale) {
  __shared__ u16 SH[2 * 2 * BUFSZ];
  const int t = threadIdx.x;

  int nwgx = gridDim.x, nwgy = gridDim.y;
  int flat = blockIdx.x + nwgx * (blockIdx.y + nwgy * blockIdx.z);
  int nwg = nwgx * nwgy * gridDim.z;
  int newflat = (flat % 8) * (nwg / 8) + flat / 8;
  const int bx = newflat % nwgx;
  int tmpf = newflat / nwgx;
  const int by = tmpf % nwgy;
  const int bz = tmpf / nwgy;

  const int m0 = by * BM;
  const int n0 = bx * BN;
  const u16* Ab = A + (long)bz * aBatch;
  const u16* Bb = B + (long)bz * bBatch;

  const int lane = t & 63;
  const int wid = t >> 6;
  const int wr = (wid >> 1) * 64;
  const int wc = (wid & 1) * 64;
  const int r16 = lane & 15;
  const int q = lane >> 4;

  const int sRow = wid * 8 + (lane >> 3);              // + p*32
  const int sCol = (((lane & 7) ^ (lane >> 3)) * 8);   // swizzled global col (u16)

  f32x4 acc[4][4] = {};
  const int rsw = r16 & 7;  // read-side XOR key

  const int nt = K / BKT;

  auto stage = [&](int c, int k0) {
    u16* aDst = SH + c * 2 * BUFSZ + wid * 512;
    u16* bDst = SH + c * 2 * BUFSZ + BUFSZ + wid * 512;
    #pragma unroll
    for (int p = 0; p < 4; ++p) {
      __builtin_amdgcn_global_load_lds(
          (const __attribute__((address_space(1))) unsigned int*)(Ab + (long)(m0 + p * 32 + sRow) * lda + k0 + sCol),
          (__attribute__((address_space(3))) unsigned int*)(aDst + p * 2048),
          16, 0, 0);
      __builtin_amdgcn_global_load_lds(
          (const __attribute__((address_space(1))) unsigned int*)(Bb + (long)(n0 + p * 32 + sRow) * ldb + k0 + sCol),
          (__attribute__((address_space(3))) unsigned int*)(bDst + p * 2048),
          16, 0, 0);
    }
  };

  stage(0, 0);

  for (int tt = 0; tt < nt; ++tt) {
    const int pre = tt + 1;
    if (pre < nt) {
      stage(pre & 1, pre * BKT);
      asm volatile("s_waitcnt vmcnt(8)" ::: "memory");
    } else {
      asm volatile("s_waitcnt vmcnt(0)" ::: "memory");
    }
    __builtin_amdgcn_s_barrier();
    __builtin_amdgcn_sched_barrier(0);

    const u16* As_b = SH + (tt & 1) * 2 * BUFSZ;
    const u16* Bs_b = As_b + BUFSZ;
    #pragma unroll
    for (int kk = 0; kk < BKT; kk += 32) {
      bf16x8 af[4], bfr[4];
      const int c0q = (kk >> 3) + q;
      const int colSw = (c0q ^ rsw) * 8;
      #pragma unroll
      for (int i = 0; i < 4; ++i) {
        af[i]  = *(const bf16x8*)&As_b[(wr + i * 16 + r16) * BKT + colSw];
        bfr[i] = *(const bf16x8*)&Bs_b[(wc + i * 16 + r16) * BKT + colSw];
      }
      #pragma unroll
      for (int i = 0; i < 4; ++i)
        #pragma unroll
        for (int j = 0; j < 4; ++j)
          acc[i][j] = __builtin_amdgcn_mfma_f32_16x16x32_bf16(af[i], bfr[j], acc[i][j], 0, 0, 0);
    }
    __builtin_amdgcn_s_barrier();
    __builtin_amdgcn_sched_barrier(0);
  }

  if (EPI == 1) {
    float cbv[4];
    #pragma unroll
    for (int j = 0; j < 4; ++j)
      cbv[j] = cbias[(long)bz * NPIX + n0 + wc + j * 16 + r16];
    #pragma unroll
    for (int i = 0; i < 4; ++i) {
      #pragma unroll
      for (int r = 0; r < 4; ++r) {
        int row = m0 + wr + i * 16 + q * 4 + r;
        float s = 0.f;
        #pragma unroll
        for (int j = 0; j < 4; ++j) {
          float p = __expf(acc[i][j][r] * scale + cbv[j]);
          s += p;
          int col = n0 + wc + j * 16 + r16;
          ((u16*)C)[(long)bz * cBatch + (long)row * ldc + col] = f2bf(p);
        }
        s += __shfl_xor(s, 1); s += __shfl_xor(s, 2);
        s += __shfl_xor(s, 4); s += __shfl_xor(s, 8);
        if (r16 == 0) atomicAdd(&L[(long)bz * NPIX + lOff + row], s);
      }
    }
    return;
  }

  if (EPI == 3) {
    float invc[4];
    #pragma unroll
    for (int j = 0; j < 4; ++j)
      invc[j] = 1.0f / L[(long)bz * NPIX + lOff + n0 + wc + j * 16 + r16];
    #pragma unroll
    for (int i = 0; i < 4; ++i) {
      #pragma unroll
      for (int r = 0; r < 4; ++r) {
        int row = m0 + wr + i * 16 + q * 4 + r;
        float bia = bias[row];
        #pragma unroll
        for (int j = 0; j < 4; ++j) {
          int col = n0 + wc + j * 16 + r16;
          long off = (long)bz * cBatch + (long)row * ldc + col;
          ((float*)C)[off] = acc[i][j][r] * invc[j] + bia +
                             resid[(long)bz * rBatch + (long)row * ldc + col];
        }
      }
    }
    return;
  }

  #pragma unroll
  for (int i = 0; i < 4; ++i) {
    #pragma unroll
    for (int r = 0; r < 4; ++r) {
      int row = m0 + wr + i * 16 + q * 4 + r;
      #pragma unroll
      for (int j = 0; j < 4; ++j) {
        int col = n0 + wc + j * 16 + r16;
        float v = acc[i][j][r] * scale;
        if (BIASMODE == 1) v += bias[row];
        if (BIASMODE == 2) v += bias[col];
        long off = (long)bz * cBatch + (long)row * ldc + col;
        if (RESID) v += resid[(long)bz * rBatch + (long)row * ldc + col];
        if (OUTF32) ((float*)C)[off] = v;
        else        ((u16*)C)[off] = f2bf(v);
      }
    }
  }
}

// ---- 256x256 NT GEMM, 8 waves, barrier-minimal counted-vmcnt pipeline ----
// exp(acc*scale + cb[col]) epilogue (direct stores) + per-block partial
// rowsums (no atomics) -> Lp[bz][bx][row]; lred_kernel sums afterwards.
__global__ __launch_bounds__(512, 1) void gemm256_exp(
    const u16* __restrict__ A, int lda, long aBatch,
    const u16* __restrict__ B, int ldb, long bBatch,
    u16* __restrict__ C, int ldc, long cBatch,
    float* __restrict__ Lp, const float* __restrict__ cb,
    int K, float scale) {
  __shared__ u16 SH[2][32768];  // [dbuf][A 16384 | B 16384]
  const int t = threadIdx.x;

  int nwgx = gridDim.x, nwgy = gridDim.y;
  int flat = blockIdx.x + nwgx * (blockIdx.y + nwgy * blockIdx.z);
  int nwg = nwgx * nwgy * gridDim.z;
  int newflat = (flat % 8) * (nwg / 8) + flat / 8;
  const int bx = newflat % nwgx;
  int tmpf = newflat / nwgx;
  const int by = tmpf % nwgy;
  const int bz = tmpf / nwgy;

  const int m0 = by * 256;
  const int n0 = bx * 256;
  const u16* Ab = A + (long)bz * aBatch;
  const u16* Bb = B + (long)bz * bBatch;
  u16* Cb = C + (long)bz * cBatch;

  const int lane = t & 63;
  const int wid = t >> 6;
  const int wrow = (wid >> 2) * 128;  // 0 / 128
  const int wcol = (wid & 3) * 64;    // 0 / 64 / 128 / 192
  const int r16 = lane & 15;
  const int q = lane >> 4;
  const int rsw = r16 & 7;

  const int sRow = t >> 3;                               // + i*64
  const int sCol = ((t & 7) ^ ((t >> 3) & 7)) * 8;       // u16

  auto stage = [&](int d, int k0) {
    u16* base = &SH[d][0];
    #pragma unroll
    for (int i = 0; i < 4; ++i)
      __builtin_amdgcn_global_load_lds(
          (const __attribute__((address_space(1))) unsigned int*)(Ab + (long)(m0 + i * 64 + sRow) * lda + k0 + sCol),
          (__attribute__((address_space(3))) unsigned int*)(base + i * 4096 + wid * 512),
          16, 0, 0);
    #pragma unroll
    for (int i = 0; i < 4; ++i)
      __builtin_amdgcn_global_load_lds(
          (const __attribute__((address_space(1))) unsigned int*)(Bb + (long)(n0 + i * 64 + sRow) * ldb + k0 + sCol),
          (__attribute__((address_space(3))) unsigned int*)(base + 16384 + i * 4096 + wid * 512),
          16, 0, 0);
  };

  f32x4 acc[8][4] = {};
  const int nt = K / 64;

  stage(0, 0);

  for (int tt = 0; tt < nt; ++tt) {
    if (tt + 1 < nt) {
      stage((tt + 1) & 1, (tt + 1) * 64);
      asm volatile("s_waitcnt vmcnt(8)" ::: "memory");
    } else {
      asm volatile("s_waitcnt vmcnt(0)" ::: "memory");
    }
    __builtin_amdgcn_s_barrier();

    const u16* As_ = &SH[tt & 1][0];
    const u16* Bs_ = As_ + 16384;
    #pragma unroll
    for (int kk = 0; kk < 2; ++kk) {
      const int cs = ((kk * 4 + q) ^ rsw) * 8;
      bf16x8 af[8], bfv[4];
      #pragma unroll
      for (int i = 0; i < 8; ++i)
        af[i] = *(const bf16x8*)&As_[(wrow + i * 16 + r16) * 64 + cs];
      #pragma unroll
      for (int i = 0; i < 4; ++i)
        bfv[i] = *(const bf16x8*)&Bs_[(wcol + i * 16 + r16) * 64 + cs];
      #pragma unroll
      for (int mi = 0; mi < 8; ++mi)
        #pragma unroll
        for (int ni = 0; ni < 4; ++ni)
          acc[mi][ni] = __builtin_amdgcn_mfma_f32_16x16x32_bf16(af[mi], bfv[ni], acc[mi][ni], 0, 0, 0);
    }
    __builtin_amdgcn_s_barrier();
  }

  // ---- epilogue: exp(+cb), direct bf16 stores, LDS partial rowsums
  float cbv[4];
  #pragma unroll
  for (int ni = 0; ni < 4; ++ni)
    cbv[ni] = cb[(long)bz * NPIX + n0 + wcol + ni * 16 + r16];
  float* Lsh = (float*)&SH[0][0];  // [2][128][4] f32 = 4KB overlay
  #pragma unroll
  for (int mi = 0; mi < 8; ++mi) {
    #pragma unroll
    for (int r = 0; r < 4; ++r) {
      int lrow = mi * 16 + q * 4 + r;           // 0..127 within wave half
      int row = m0 + wrow + lrow;
      float s = 0.f;
      #pragma unroll
      for (int ni = 0; ni < 4; ++ni) {
        float p = __expf(acc[mi][ni][r] * scale + cbv[ni]);
        s += p;
        Cb[(long)row * ldc + n0 + wcol + ni * 16 + r16] = f2bf(p);
      }
      s += __shfl_xor(s, 1); s += __shfl_xor(s, 2);
      s += __shfl_xor(s, 4); s += __shfl_xor(s, 8);
      if (r16 == 0) Lsh[((wrow >> 7) * 128 + lrow) * 4 + (wcol >> 6)] = s;
    }
  }
  __syncthreads();
  if (t < 256) {
    const float* lr = &Lsh[t * 4];
    Lp[((long)bz * 16 + bx) * NPIX + m0 + t] = lr[0] + lr[1] + lr[2] + lr[3];
  }
}

extern "C" void kernel_launch(void* const* d_in, const int* in_sizes, int n_in,
                              void* d_out, int out_size, void* d_ws, size_t ws_size,
                              hipStream_t stream) {
  const float* x   = (const float*)d_in[0];
  const float* gnw = (const float*)d_in[1];
  const float* gnb = (const float*)d_in[2];
  const float* wq  = (const float*)d_in[3];
  const float* bq  = (const float*)d_in[4];
  const float* wk  = (const float*)d_in[5];
  const float* bk_ = (const float*)d_in[6];
  const float* wv  = (const float*)d_in[7];
  const float* bv  = (const float*)d_in[8];
  const float* wo  = (const float*)d_in[9];
  const float* bo  = (const float*)d_in[10];
  float* out = (float*)d_out;
  (void)bk_;

  char* wsp = (char*)d_ws;
  auto alloc = [&](size_t bytes) {
    char* r = wsp; wsp += (bytes + 255) & ~(size_t)255; return r;
  };
  const size_t WSZ = (size_t)CC * CC;      // 512*512 elements
  u16* wA = (u16*)alloc(2 * WSZ * 2);      // [wqT | wo]
  u16* wB = (u16*)alloc(2 * WSZ * 2);      // [wkT | wvT]
  u16* wC = (u16*)alloc(2 * WSZ * 2);      // [Mqk | wov]
  float* ub    = (float*)alloc(CC * 4);
  float* wobv  = (float*)alloc(CC * 4);
  float* cb    = (float*)alloc((size_t)NB * NPIX * 4);
  float* stats = (float*)alloc((size_t)NB * NG * 2 * 4);
  float* lsum  = (float*)alloc((size_t)NB * NPIX * 4);
  float* lpart = (float*)alloc((size_t)NB * 16 * NPIX * 4);
  u16* hn  = (u16*)alloc((size_t)NB * NPIX * CC * 2);
  u16* k2  = (u16*)alloc((size_t)NB * NPIX * CC * 2);   // [B][j][a]
  u16* von = (u16*)alloc((size_t)NB * CC * NPIX * 2);   // [B][o][j]
  size_t used = (size_t)(wsp - (char*)d_ws);
  size_t rem = ws_size > used ? ws_size - used : 0;
  int CH = 256;
  if ((size_t)NB * 1024 * NPIX * 2 <= rem) CH = 1024;
  if ((size_t)NB * 4096 * NPIX * 2 <= rem) CH = 4096;
  u16* SP = (u16*)alloc((size_t)NB * CH * NPIX * 2);

  dim3 blk(256);
  const float scale = 0.044194173824159216f;  // 512^-0.5

  // weight preprocessing
  f2bfT_kernel<<<dim3(8, 8, 3), blk, 0, stream>>>(wq, wk, wv, wA, wB, wB + WSZ);
  f2bf1_kernel<<<CC * CC / 1024, blk, 0, stream>>>(wo, wA + WSZ);
  ubias_kernel<<<CC / 256, blk, 0, stream>>>(wB, bq, ub);
  wobv_kernel<<<CC / 256, blk, 0, stream>>>(wo, bv, bo, wobv);
  hipMemsetAsync(lsum, 0, (size_t)NB * NPIX * 4, stream);

  // Mqk = wq^T*wk ; wov = wo*wv  (batched tiny GEMM, bf16 out)
  gemm_nt<0, 0, 0, 0><<<dim3(CC / BN, CC / BM, 2), blk, 0, stream>>>(
      wA, CC, (long)WSZ, wB, CC, (long)WSZ, wC, CC, (long)WSZ,
      nullptr, nullptr, 0, nullptr, 0, nullptr, CC, 1.0f);

  gn_stats_kernel<<<NB * NG, blk, 0, stream>>>(x, stats);
  gn_apply_kernel<<<dim3(NPIX / 64, CC / 64, NB), blk, 0, stream>>>(x, stats, gnw, gnb, hn);
  cb_kernel<<<NB * NPIX / 256, blk, 0, stream>>>(hn, ub, cb, scale);

  // k2[j,a] = sum_b hn[j,b] * Mqk[a,b]   (M=NPIX, N=CC)
  gemm_nt<0, 0, 0, 0><<<dim3(CC / BN, NPIX / BM, NB), blk, 0, stream>>>(
      hn, CC, (long)NPIX * CC, wC, CC, 0, k2, CC, (long)NPIX * CC,
      nullptr, nullptr, 0, nullptr, 0, nullptr, CC, 1.0f);
  // von[o,j] = sum_ch wov[o,ch] * hn[j,ch]   (M=CC, N=NPIX)
  gemm_nt<0, 0, 0, 0><<<dim3(NPIX / BN, CC / BM, NB), blk, 0, stream>>>(
      wC + WSZ, CC, 0, hn, CC, (long)NPIX * CC, von, NPIX, (long)CC * NPIX,
      nullptr, nullptr, 0, nullptr, 0, nullptr, CC, 1.0f);

  for (int i0 = 0; i0 < NPIX; i0 += CH) {
    // P[i,j] = exp(scale*sum_a hn[i,a]*k2[j,a] + cb[j]); rowsums -> lsum
    if (CH == 4096) {
      gemm256_exp<<<dim3(NPIX / 256, NPIX / 256, NB), dim3(512), 0, stream>>>(
          hn, CC, (long)NPIX * CC, k2, CC, (long)NPIX * CC,
          SP, NPIX, (long)CH * NPIX, lpart, cb, CC, scale);
      lred_kernel<<<NB * NPIX / 256, blk, 0, stream>>>(lpart, lsum);
    } else {
      gemm_nt<0, 0, 0, 1><<<dim3(NPIX / BN, CH / BM, NB), blk, 0, stream>>>(
          hn + (long)i0 * CC, CC, (long)NPIX * CC, k2, CC, (long)NPIX * CC,
          SP, NPIX, (long)CH * NPIX, nullptr, nullptr, 0, lsum, i0, cb, CC, scale);
    }
    // out[o, i0+i] = (sum_j P[i,j]*von[o,j]) / L[i0+i] + wobv[o] + x[o, i0+i]
    gemm_nt<1, 1, 1, 3><<<dim3(CH / BN, CC / BM, NB), blk, 0, stream>>>(
        von, NPIX, (long)CC * NPIX, SP, NPIX, (long)CH * NPIX,
        out + i0, NPIX, (long)CC * NPIX, wobv, x + i0, (long)CC * NPIX,
        lsum, i0, nullptr, NPIX, 1.0f);
  }
}

// Round 13
// 152.858 us; speedup vs baseline: 1.3208x; 1.3208x over previous
//
#include <hip/hip_runtime.h>

#define CC 512
#define NPIX 4096
#define NB 2
#define NG 32
#define GSIZE 16
#define EPS 1e-6f

typedef unsigned short u16;
typedef __bf16 bf16x8 __attribute__((ext_vector_type(8)));
typedef float f32x4 __attribute__((ext_vector_type(4)));

__device__ __forceinline__ float bf2f(u16 u) {
  union { unsigned int i; float f; } c; c.i = ((unsigned int)u) << 16; return c.f;
}
__device__ __forceinline__ u16 f2bf(float f) {
  union { float f; unsigned int i; } c; c.f = f;
  unsigned int u = c.i;
  return (u16)((u + 0x7fffu + ((u >> 16) & 1u)) >> 16);
}

// ---- fp32 -> bf16 conversion for 4 weight matrices in one launch ----
__global__ __launch_bounds__(256) void f2bf4x4_kernel(
    const float* __restrict__ s0, const float* __restrict__ s1,
    const float* __restrict__ s2, const float* __restrict__ s3,
    u16* __restrict__ d0, u16* __restrict__ d1,
    u16* __restrict__ d2, u16* __restrict__ d3) {
  const float* s; u16* d;
  switch (blockIdx.y) {
    case 0: s = s0; d = d0; break;
    case 1: s = s1; d = d1; break;
    case 2: s = s2; d = d2; break;
    default: s = s3; d = d3; break;
  }
  int i = blockIdx.x * 256 + threadIdx.x;
  float4 v = ((const float4*)s)[i];
  uint2 pk;
  pk.x = (unsigned)f2bf(v.x) | ((unsigned)f2bf(v.y) << 16);
  pk.y = (unsigned)f2bf(v.z) | ((unsigned)f2bf(v.w) << 16);
  ((uint2*)d)[i] = pk;
}

// ---- concat two 512-float bias vectors ----
__global__ __launch_bounds__(256) void concat2_kernel(const float* __restrict__ a,
                                                      const float* __restrict__ b,
                                                      float* __restrict__ o) {
  int i = blockIdx.x * 256 + threadIdx.x;  // 0..1023
  o[i] = (i < CC) ? a[i] : b[i - CC];
}

// ---- GroupNorm stats, stage 1: 8 partial (sum,sumsq) per (b,g) ----
// 512 blocks (2 blocks/CU-ish) instead of 64 -> latency-hiding via TLP.
__global__ __launch_bounds__(256) void gn_stats_part(const float* __restrict__ x,
                                                     float* __restrict__ part) {
  int bg = blockIdx.x >> 3;   // 0..63
  int ch = blockIdx.x & 7;    // 0..7
  const int CHUNK4 = GSIZE * NPIX / 8 / 4;  // 2048 float4
  const float4* p = (const float4*)(x + (long)bg * (GSIZE * NPIX)) + ch * CHUNK4;
  float s = 0.f, ss = 0.f;
  for (int i = threadIdx.x; i < CHUNK4; i += 256) {
    float4 v = p[i];
    s  += v.x + v.y + v.z + v.w;
    ss += v.x * v.x + v.y * v.y + v.z * v.z + v.w * v.w;
  }
  for (int off = 32; off; off >>= 1) { s += __shfl_xor(s, off); ss += __shfl_xor(ss, off); }
  __shared__ float rs[4], rss[4];
  int wid = threadIdx.x >> 6;
  if ((threadIdx.x & 63) == 0) { rs[wid] = s; rss[wid] = ss; }
  __syncthreads();
  if (threadIdx.x == 0) {
    part[blockIdx.x * 2]     = rs[0] + rs[1] + rs[2] + rs[3];
    part[blockIdx.x * 2 + 1] = rss[0] + rss[1] + rss[2] + rss[3];
  }
}

// ---- GroupNorm stats, stage 2: finalize mean/rstd (64 threads) ----
__global__ __launch_bounds__(64) void gn_stats_fin(const float* __restrict__ part,
                                                   float* __restrict__ stats) {
  int bg = threadIdx.x;  // 0..63
  float s = 0.f, ss = 0.f;
  #pragma unroll
  for (int c = 0; c < 8; ++c) {
    s  += part[(bg * 8 + c) * 2];
    ss += part[(bg * 8 + c) * 2 + 1];
  }
  float mean = s / (float)(GSIZE * NPIX);
  float var = ss / (float)(GSIZE * NPIX) - mean * mean;
  stats[bg * 2] = mean;
  stats[bg * 2 + 1] = rsqrtf(var + EPS);
}

// ---- GN apply + transpose: x[b][c][n] -> hn[b][n][c] (bf16) ----
__global__ __launch_bounds__(256) void gn_apply_kernel(const float* __restrict__ x,
                                                       const float* __restrict__ stats,
                                                       const float* __restrict__ gw,
                                                       const float* __restrict__ gb,
                                                       u16* __restrict__ hn) {
  int n0 = blockIdx.x * 64, c0 = blockIdx.y * 64, b = blockIdx.z;
  __shared__ float tile[64][65];
  int t = threadIdx.x;
  int nj = t & 63, cw = t >> 6;
  #pragma unroll
  for (int r = 0; r < 16; ++r) {
    int ci = cw * 16 + r;
    int c = c0 + ci;
    float mean = stats[(b * NG + (c >> 4)) * 2];
    float rstd = stats[(b * NG + (c >> 4)) * 2 + 1];
    float v = x[((long)b * CC + c) * NPIX + n0 + nj];
    tile[ci][nj] = (v - mean) * rstd * gw[c] + gb[c];
  }
  __syncthreads();
  #pragma unroll
  for (int r = 0; r < 16; ++r) {
    int nn = cw * 16 + r;
    hn[((long)b * NPIX + n0 + nn) * CC + c0 + nj] = f2bf(tile[nj][nn]);
  }
}

// ---- reduce 16 per-bx partial rowsums into L[bz][row] ----
__global__ __launch_bounds__(256) void lred_kernel(const float* __restrict__ Lp,
                                                   float* __restrict__ L) {
  int i = blockIdx.x * 256 + threadIdx.x;  // bz*NPIX + row
  int bz = i / NPIX, row = i % NPIX;
  float s = 0.f;
  #pragma unroll
  for (int b = 0; b < 16; ++b) s += Lp[((long)bz * 16 + b) * NPIX + row];
  L[i] = s;
}

// ---- 128x128 NT GEMM (2-phase counted-vmcnt) ----
// EPI: 0 = plain (+bias/resid per BIASMODE/RESID), 1 = exp+rowsum-atomics
// (bf16 out, unnormalized softmax numerator), 2 = divide-by-L (bf16 out).
#define BM 128
#define BN 128
#define BKT 64
#define BUFSZ 8192  // u16 per half-buffer (one 128x64 operand tile)

template<int OUTF32, int BIASMODE, int RESID, int EPI>
__global__ __launch_bounds__(256) void gemm_nt(
    const u16* __restrict__ A, int lda, long aBatch,
    const u16* __restrict__ B, int ldb, long bBatch,
    void* __restrict__ C, int ldc, long cBatch,
    const float* __restrict__ bias,
    const float* __restrict__ resid, long rBatch,
    float* __restrict__ L, int lOff,
    int K, float scale) {
  __shared__ u16 SH[2 * 2 * BUFSZ];
  const int t = threadIdx.x;

  int nwgx = gridDim.x, nwgy = gridDim.y;
  int flat = blockIdx.x + nwgx * (blockIdx.y + nwgy * blockIdx.z);
  int nwg = nwgx * nwgy * gridDim.z;
  int newflat = (flat % 8) * (nwg / 8) + flat / 8;
  const int bx = newflat % nwgx;
  int tmpf = newflat / nwgx;
  const int by = tmpf % nwgy;
  const int bz = tmpf / nwgy;

  const int m0 = by * BM;
  const int n0 = bx * BN;
  const u16* Ab = A + (long)bz * aBatch;
  const u16* Bb = B + (long)bz * bBatch;

  const int lane = t & 63;
  const int wid = t >> 6;
  const int wr = (wid >> 1) * 64;
  const int wc = (wid & 1) * 64;
  const int r16 = lane & 15;
  const int q = lane >> 4;

  const int sRow = wid * 8 + (lane >> 3);              // + p*32
  const int sCol = (((lane & 7) ^ (lane >> 3)) * 8);   // swizzled global col (u16)

  f32x4 acc[4][4] = {};
  const int rsw = r16 & 7;  // read-side XOR key

  const int nt = K / BKT;

  auto stage = [&](int c, int k0) {
    u16* aDst = SH + c * 2 * BUFSZ + wid * 512;
    u16* bDst = SH + c * 2 * BUFSZ + BUFSZ + wid * 512;
    #pragma unroll
    for (int p = 0; p < 4; ++p) {
      __builtin_amdgcn_global_load_lds(
          (const __attribute__((address_space(1))) unsigned int*)(Ab + (long)(m0 + p * 32 + sRow) * lda + k0 + sCol),
          (__attribute__((address_space(3))) unsigned int*)(aDst + p * 2048),
          16, 0, 0);
      __builtin_amdgcn_global_load_lds(
          (const __attribute__((address_space(1))) unsigned int*)(Bb + (long)(n0 + p * 32 + sRow) * ldb + k0 + sCol),
          (__attribute__((address_space(3))) unsigned int*)(bDst + p * 2048),
          16, 0, 0);
    }
  };

  stage(0, 0);

  for (int tt = 0; tt < nt; ++tt) {
    const int pre = tt + 1;
    if (pre < nt) {
      stage(pre & 1, pre * BKT);
      asm volatile("s_waitcnt vmcnt(8)" ::: "memory");
    } else {
      asm volatile("s_waitcnt vmcnt(0)" ::: "memory");
    }
    __builtin_amdgcn_s_barrier();
    __builtin_amdgcn_sched_barrier(0);

    const u16* As_b = SH + (tt & 1) * 2 * BUFSZ;
    const u16* Bs_b = As_b + BUFSZ;
    #pragma unroll
    for (int kk = 0; kk < BKT; kk += 32) {
      bf16x8 af[4], bfr[4];
      const int c0q = (kk >> 3) + q;
      const int colSw = (c0q ^ rsw) * 8;
      #pragma unroll
      for (int i = 0; i < 4; ++i) {
        af[i]  = *(const bf16x8*)&As_b[(wr + i * 16 + r16) * BKT + colSw];
        bfr[i] = *(const bf16x8*)&Bs_b[(wc + i * 16 + r16) * BKT + colSw];
      }
      #pragma unroll
      for (int i = 0; i < 4; ++i)
        #pragma unroll
        for (int j = 0; j < 4; ++j)
          acc[i][j] = __builtin_amdgcn_mfma_f32_16x16x32_bf16(af[i], bfr[j], acc[i][j], 0, 0, 0);
    }
    __builtin_amdgcn_s_barrier();
    __builtin_amdgcn_sched_barrier(0);
  }

  if (EPI == 1) {
    #pragma unroll
    for (int i = 0; i < 4; ++i) {
      #pragma unroll
      for (int r = 0; r < 4; ++r) {
        int row = m0 + wr + i * 16 + q * 4 + r;
        float s = 0.f;
        #pragma unroll
        for (int j = 0; j < 4; ++j) {
          float p = __expf(acc[i][j][r] * scale);
          s += p;
          int col = n0 + wc + j * 16 + r16;
          ((u16*)C)[(long)bz * cBatch + (long)row * ldc + col] = f2bf(p);
        }
        s += __shfl_xor(s, 1); s += __shfl_xor(s, 2);
        s += __shfl_xor(s, 4); s += __shfl_xor(s, 8);
        if (r16 == 0) atomicAdd(&L[(long)bz * NPIX + lOff + row], s);
      }
    }
    return;
  }

  #pragma unroll
  for (int i = 0; i < 4; ++i) {
    #pragma unroll
    for (int r = 0; r < 4; ++r) {
      int row = m0 + wr + i * 16 + q * 4 + r;
      float inv = 1.0f;
      if (EPI == 2) inv = 1.0f / L[(long)bz * NPIX + lOff + row];
      #pragma unroll
      for (int j = 0; j < 4; ++j) {
        int col = n0 + wc + j * 16 + r16;
        float v = acc[i][j][r] * scale;
        if (EPI == 2) v *= inv;
        if (BIASMODE == 1) v += bias[row];
        if (BIASMODE == 2) v += bias[col];
        long off = (long)bz * cBatch + (long)row * ldc + col;
        if (RESID) v += resid[(long)bz * rBatch + (long)row * ldc + col];
        if (OUTF32) ((float*)C)[off] = v;
        else        ((u16*)C)[off] = f2bf(v);
      }
    }
  }
}

// ---- 256x256 NT GEMM, 8 waves, barrier-minimal counted-vmcnt pipeline ----
// exp epilogue (direct stores) + per-block partial rowsums (NO atomics):
// wave partials -> 4KB LDS overlay -> one coalesced f32 store per row into
// Lp[bz][bx][row]; lred_kernel sums the 16 partials afterwards.
__global__ __launch_bounds__(512, 1) void gemm256_exp(
    const u16* __restrict__ A, int lda, long aBatch,
    const u16* __restrict__ B, int ldb, long bBatch,
    u16* __restrict__ C, int ldc, long cBatch,
    float* __restrict__ Lp,
    int K, float scale) {
  __shared__ u16 SH[2][32768];  // [dbuf][A 16384 | B 16384]
  const int t = threadIdx.x;

  int nwgx = gridDim.x, nwgy = gridDim.y;
  int flat = blockIdx.x + nwgx * (blockIdx.y + nwgy * blockIdx.z);
  int nwg = nwgx * nwgy * gridDim.z;
  int newflat = (flat % 8) * (nwg / 8) + flat / 8;
  const int bx = newflat % nwgx;
  int tmpf = newflat / nwgx;
  const int by = tmpf % nwgy;
  const int bz = tmpf / nwgy;

  const int m0 = by * 256;
  const int n0 = bx * 256;
  const u16* Ab = A + (long)bz * aBatch;
  const u16* Bb = B + (long)bz * bBatch;
  u16* Cb = C + (long)bz * cBatch;

  const int lane = t & 63;
  const int wid = t >> 6;
  const int wrow = (wid >> 2) * 128;  // 0 / 128
  const int wcol = (wid & 3) * 64;    // 0 / 64 / 128 / 192
  const int r16 = lane & 15;
  const int q = lane >> 4;
  const int rsw = r16 & 7;

  const int sRow = t >> 3;                               // + i*64
  const int sCol = ((t & 7) ^ ((t >> 3) & 7)) * 8;       // u16

  auto stage = [&](int d, int k0) {
    u16* base = &SH[d][0];
    #pragma unroll
    for (int i = 0; i < 4; ++i)
      __builtin_amdgcn_global_load_lds(
          (const __attribute__((address_space(1))) unsigned int*)(Ab + (long)(m0 + i * 64 + sRow) * lda + k0 + sCol),
          (__attribute__((address_space(3))) unsigned int*)(base + i * 4096 + wid * 512),
          16, 0, 0);
    #pragma unroll
    for (int i = 0; i < 4; ++i)
      __builtin_amdgcn_global_load_lds(
          (const __attribute__((address_space(1))) unsigned int*)(Bb + (long)(n0 + i * 64 + sRow) * ldb + k0 + sCol),
          (__attribute__((address_space(3))) unsigned int*)(base + 16384 + i * 4096 + wid * 512),
          16, 0, 0);
  };

  f32x4 acc[8][4] = {};
  const int nt = K / 64;

  stage(0, 0);

  for (int tt = 0; tt < nt; ++tt) {
    if (tt + 1 < nt) {
      stage((tt + 1) & 1, (tt + 1) * 64);
      asm volatile("s_waitcnt vmcnt(8)" ::: "memory");
    } else {
      asm volatile("s_waitcnt vmcnt(0)" ::: "memory");
    }
    __builtin_amdgcn_s_barrier();

    const u16* As_ = &SH[tt & 1][0];
    const u16* Bs_ = As_ + 16384;
    #pragma unroll
    for (int kk = 0; kk < 2; ++kk) {
      const int cs = ((kk * 4 + q) ^ rsw) * 8;
      bf16x8 af[8], bfv[4];
      #pragma unroll
      for (int i = 0; i < 8; ++i)
        af[i] = *(const bf16x8*)&As_[(wrow + i * 16 + r16) * 64 + cs];
      #pragma unroll
      for (int i = 0; i < 4; ++i)
        bfv[i] = *(const bf16x8*)&Bs_[(wcol + i * 16 + r16) * 64 + cs];
      #pragma unroll
      for (int mi = 0; mi < 8; ++mi)
        #pragma unroll
        for (int ni = 0; ni < 4; ++ni)
          acc[mi][ni] = __builtin_amdgcn_mfma_f32_16x16x32_bf16(af[mi], bfv[ni], acc[mi][ni], 0, 0, 0);
    }
    __builtin_amdgcn_s_barrier();
  }

  // ---- epilogue: exp, direct bf16 stores, LDS partial rowsums (no atomics)
  float* Lsh = (float*)&SH[0][0];  // [2][128][4] f32 = 4KB overlay
  #pragma unroll
  for (int mi = 0; mi < 8; ++mi) {
    #pragma unroll
    for (int r = 0; r < 4; ++r) {
      int lrow = mi * 16 + q * 4 + r;           // 0..127 within wave half
      int row = m0 + wrow + lrow;
      float s = 0.f;
      #pragma unroll
      for (int ni = 0; ni < 4; ++ni) {
        float p = __expf(acc[mi][ni][r] * scale);
        s += p;
        Cb[(long)row * ldc + n0 + wcol + ni * 16 + r16] = f2bf(p);
      }
      s += __shfl_xor(s, 1); s += __shfl_xor(s, 2);
      s += __shfl_xor(s, 4); s += __shfl_xor(s, 8);
      if (r16 == 0) Lsh[((wrow >> 7) * 128 + lrow) * 4 + (wcol >> 6)] = s;
    }
  }
  __syncthreads();
  if (t < 256) {
    const float* lr = &Lsh[t * 4];
    Lp[((long)bz * 16 + bx) * NPIX + m0 + t] = lr[0] + lr[1] + lr[2] + lr[3];
  }
}

extern "C" void kernel_launch(void* const* d_in, const int* in_sizes, int n_in,
                              void* d_out, int out_size, void* d_ws, size_t ws_size,
                              hipStream_t stream) {
  const float* x   = (const float*)d_in[0];
  const float* gnw = (const float*)d_in[1];
  const float* gnb = (const float*)d_in[2];
  const float* wq  = (const float*)d_in[3];
  const float* bq  = (const float*)d_in[4];
  const float* wk  = (const float*)d_in[5];
  const float* bk_ = (const float*)d_in[6];
  const float* wv  = (const float*)d_in[7];
  const float* bv  = (const float*)d_in[8];
  const float* wo  = (const float*)d_in[9];
  const float* bo  = (const float*)d_in[10];
  float* out = (float*)d_out;

  char* wsp = (char*)d_ws;
  auto alloc = [&](size_t bytes) {
    char* r = wsp; wsp += (bytes + 255) & ~(size_t)255; return r;
  };
  u16* wqb = (u16*)alloc((size_t)CC * CC * 2);
  u16* wkb = (u16*)alloc((size_t)CC * CC * 2);
  u16* wvb = (u16*)alloc((size_t)CC * CC * 2);
  u16* wob = (u16*)alloc((size_t)CC * CC * 2);
  float* bqk = (float*)alloc((size_t)2 * CC * 4);
  float* gpart = (float*)alloc((size_t)NB * NG * 8 * 2 * 4);
  float* stats = (float*)alloc((size_t)NB * NG * 2 * 4);
  float* lsum = (float*)alloc((size_t)NB * NPIX * 4);
  float* lpart = (float*)alloc((size_t)NB * 16 * NPIX * 4);
  u16* hn  = (u16*)alloc((size_t)NB * NPIX * CC * 2);
  u16* qkt = (u16*)alloc((size_t)NB * NPIX * (2 * CC) * 2);  // [B][N][1024] = q|k
  u16* vcn = (u16*)alloc((size_t)NB * CC * NPIX * 2);
  u16* ot  = (u16*)alloc((size_t)NB * NPIX * CC * 2);
  size_t used = (size_t)(wsp - (char*)d_ws);
  size_t rem = ws_size > used ? ws_size - used : 0;
  int CH = 256;
  if ((size_t)NB * 1024 * NPIX * 2 <= rem) CH = 1024;
  if ((size_t)NB * 4096 * NPIX * 2 <= rem) CH = 4096;
  u16* SP = (u16*)alloc((size_t)NB * CH * NPIX * 2);

  dim3 blk(256);
  f2bf4x4_kernel<<<dim3(CC * CC / 1024, 4), blk, 0, stream>>>(
      wq, wk, wv, wo, wqb, wkb, wvb, wob);
  concat2_kernel<<<2 * CC / 256, blk, 0, stream>>>(bq, bk_, bqk);
  hipMemsetAsync(lsum, 0, (size_t)NB * NPIX * 4, stream);

  gn_stats_part<<<NB * NG * 8, blk, 0, stream>>>(x, gpart);
  gn_stats_fin<<<1, 64, 0, stream>>>(gpart, stats);
  gn_apply_kernel<<<dim3(NPIX / 64, CC / 64, NB), blk, 0, stream>>>(x, stats, gnw, gnb, hn);

  // Fused QK: qk_t[n, o] = sum_c hn[n,c]*wqk[o,c] + bqk[o], o in [0,1024)
  gemm_nt<0, 2, 0, 0><<<dim3(2 * CC / BN, NPIX / BM, NB), blk, 0, stream>>>(
      hn, CC, (long)NPIX * CC, wqb, CC, 0, qkt, 2 * CC, (long)NPIX * 2 * CC,
      bqk, nullptr, 0, nullptr, 0, CC, 1.0f);
  // V: v_cn[c,n] = sum_ch wv[c,ch]*hn[n,ch] + bv[c]  (M=CC, N=NPIX)
  gemm_nt<0, 1, 0, 0><<<dim3(NPIX / BN, CC / BM, NB), blk, 0, stream>>>(
      wvb, CC, 0, hn, CC, (long)NPIX * CC, vcn, NPIX, (long)CC * NPIX,
      bv, nullptr, 0, nullptr, 0, CC, 1.0f);

  const u16* qt = qkt;
  const u16* kt = qkt + CC;
  const float scale = 0.044194173824159216f;  // 512^-0.5
  for (int i0 = 0; i0 < NPIX; i0 += CH) {
    // P[i,j] = exp(scale * sum_c q[i,c]*k[j,c]); rowsums -> lpart -> lsum
    if (CH == 4096) {
      gemm256_exp<<<dim3(NPIX / 256, NPIX / 256, NB), dim3(512), 0, stream>>>(
          qt, 2 * CC, (long)NPIX * 2 * CC, kt, 2 * CC, (long)NPIX * 2 * CC,
          SP, NPIX, (long)CH * NPIX, lpart, CC, scale);
      lred_kernel<<<NB * NPIX / 256, blk, 0, stream>>>(lpart, lsum);
    } else {
      gemm_nt<0, 0, 0, 1><<<dim3(NPIX / BN, CH / BM, NB), blk, 0, stream>>>(
          qt + (long)i0 * 2 * CC, 2 * CC, (long)NPIX * 2 * CC, kt, 2 * CC, (long)NPIX * 2 * CC,
          SP, NPIX, (long)CH * NPIX, nullptr, nullptr, 0, lsum, i0, CC, scale);
    }
    // O_t[i,c] = (sum_j P[i,j]*v_cn[c,j]) / L[i]
    gemm_nt<0, 0, 0, 2><<<dim3(CC / BN, CH / BM, NB), blk, 0, stream>>>(
        SP, NPIX, (long)CH * NPIX, vcn, NPIX, (long)CC * NPIX,
        ot + (long)i0 * CC, CC, (long)NPIX * CC, nullptr, nullptr, 0, lsum, i0, NPIX, 1.0f);
  }

  // out[o,n] = sum_c wo[o,c]*ot[n,c] + bo[o] + x[o,n]  (M=CC, N=NPIX), f32 out
  gemm_nt<1, 1, 1, 0><<<dim3(NPIX / BN, CC / BM, NB), blk, 0, stream>>>(
      wob, CC, 0, ot, CC, (long)NPIX * CC, out, NPIX, (long)CC * NPIX,
      bo, x, (long)CC * NPIX, nullptr, 0, CC, 1.0f);
}